// Round 1
// baseline (107.492 us; speedup 1.0000x reference)
//
#include <hip/hip_runtime.h>
#include <math.h>

#define BLOCK 64
#define BATCH 16384
#define EPB 8      // elements per block: 8 lanes per element
#define EP 9       // element-dim stride for scalar per-element LDS arrays
#define NDOF 7
#define ACTION_RANGE 50.0f
#define MAX_VEL 20.0f
#define HSTEP 0.1f

// BLOCK==64 -> exactly one wave per workgroup. DS ops from a single wave are
// processed in order, so cross-lane LDS communication needs no s_barrier —
// only a compiler-level fence to forbid reordering/caching of LDS accesses.
// (The previous kernel already relied on in-order DS for the barrier-free
// sQh forward->backward handoff.)
#define WSYNC() asm volatile("" ::: "memory")

__device__ __forceinline__ void mat3_mul(float* C, const float* A, const float* B) {
#pragma unroll
  for (int r = 0; r < 3; r++) {
#pragma unroll
    for (int c = 0; c < 3; c++) {
      C[r*3+c] = A[r*3+0]*B[0*3+c] + A[r*3+1]*B[1*3+c] + A[r*3+2]*B[2*3+c];
    }
  }
}

__device__ __forceinline__ void mat3_vec(float* y, const float* A, const float* x) {
#pragma unroll
  for (int r = 0; r < 3; r++)
    y[r] = A[r*3+0]*x[0] + A[r*3+1]*x[1] + A[r*3+2]*x[2];
}

__device__ __forceinline__ void mat3T_vec(float* y, const float* A, const float* x) {
#pragma unroll
  for (int r = 0; r < 3; r++)
    y[r] = A[0*3+r]*x[0] + A[1*3+r]*x[1] + A[2*3+r]*x[2];
}

__device__ __forceinline__ void cross3(float* y, const float* a, const float* b) {
  y[0] = a[1]*b[2] - a[2]*b[1];
  y[1] = a[2]*b[0] - a[0]*b[2];
  y[2] = a[0]*b[1] - a[1]*b[0];
}

// Rodrigues-direct for UNIT axis w (W^2 = ww^T - I):
//   R = cI + sW + (1-c)ww^T ;  G v with G = sI + (1-c)W + (th-s)ww^T
__device__ __forceinline__ void exp_se3(const float* A6, float th, float* R, float* p) {
  float w0 = A6[0], w1 = A6[1], w2 = A6[2];
  float s = __sinf(th);
  float c = __cosf(th);
  float omc = 1.0f - c, tms = th - s;
  float p00 = w0*w0, p01 = w0*w1, p02 = w0*w2;
  float p11 = w1*w1, p12 = w1*w2, p22 = w2*w2;
  R[0] = c + omc*p00;       R[1] = omc*p01 - s*w2;   R[2] = omc*p02 + s*w1;
  R[3] = omc*p01 + s*w2;    R[4] = c + omc*p11;      R[5] = omc*p12 - s*w0;
  R[6] = omc*p02 - s*w1;    R[7] = omc*p12 + s*w0;   R[8] = c + omc*p22;
  float G0 = s + tms*p00,    G1 = tms*p01 - omc*w2,  G2 = tms*p02 + omc*w1;
  float G3 = tms*p01 + omc*w2, G4 = s + tms*p11,     G5 = tms*p12 - omc*w0;
  float G6 = tms*p02 - omc*w1, G7 = tms*p12 + omc*w0, G8 = s + tms*p22;
  p[0] = G0*A6[3] + G1*A6[4] + G2*A6[5];
  p[1] = G3*A6[3] + G4*A6[4] + G5*A6[5];
  p[2] = G6*A6[3] + G7*A6[4] + G8*A6[5];
}

__device__ __forceinline__ float wrap_pi(float x) {
  const float PI_F   = 3.14159265358979323846f;
  const float TWO_PI = 6.28318530717958647692f;
  float a = x + PI_F;
  float r = a - floorf(a * (1.0f / TWO_PI)) * TWO_PI;
  return r - PI_F;
}

// R14 = R13 (41.5us/dispatch) + DS-pipe/barrier/tail attack:
//  (a) Bm eliminated algebraically: Bm = hat(Tp)*R, so Bm*x = Tp x (R*x),
//      Bm^T*x = R^T*(x x Tp). Adjoint payload 18 -> 12 floats/joint.
//  (b) Per-element sRB[e][84] layout, joint stride 12 floats (48B): the
//      broadcast is 3x ds_read_b128/joint instead of 18x b32. Element stride
//      84 words (84%32==20) -> distinct bank-quads per group, conflict-free.
//      sQh: [e][60], 2x b128 per joint, same skew property (60%32==28).
//  (c) All __syncthreads removed (single-wave WG + in-order DS) -> no
//      s_barrier / lgkmcnt(0) full drains; WSYNC() is a free compiler fence.
//  (d) A (all joints), own-joint M^-1, lane-7 tau cached in registers.
//  (e) Tail FK = per-lane leaf M_r*exp(A_r q_r) + 3-step shuffle tree
//      (full-lane work instead of 1/8-masked serial chain); qfL LDS dropped.
__global__ __launch_bounds__(BLOCK, 1) void arm_rk4_kernel(
    const float* __restrict__ g_state, const float* __restrict__ g_action,
    const float* __restrict__ g_M, const float* __restrict__ g_A,
    const float* __restrict__ g_G, const float* __restrict__ g_grav,
    float* __restrict__ g_out_state, float* __restrict__ g_out_ee)
{
  __shared__ alignas(16) float sRB[8][84];   // joint i at [e][i*12]: R[0..8], Tp[3]
  __shared__ alignas(16) float sQh[8][60];   // joint i at [e][i*8]: Qw[3],pad,Qv[3],pad
  __shared__ alignas(16) float sIRp[7][12];  // M_i^-1: R^T[9], (-R^T p)[3]
  __shared__ alignas(16) float sMRp[8][12];  // M_i: R[9], p[3]
  __shared__ alignas(16) float sA2[7][8];    // w[3], v[3], pad2
  __shared__ alignas(16) float sG4[7][4];
  __shared__ float sg[4];
  __shared__ float qaccL[NDOF*EP];
  __shared__ float MllL[28*EP];

  const int tid  = threadIdx.x;
  const int e    = tid >> 3;      // element slot 0..7
  const int r    = tid & 7;       // role 0..7
  const int base = tid & 0x38;    // first lane of this element group
  const int b    = blockIdx.x * EPB + e;

  if (tid < 8) {
    const float* Mi = g_M + tid*16;
    float a1[3] = {Mi[0], Mi[4], Mi[8]};
    float a2[3] = {Mi[1], Mi[5], Mi[9]};
    float p[3]  = {Mi[3], Mi[7], Mi[11]};
    float n1 = sqrtf(a1[0]*a1[0] + a1[1]*a1[1] + a1[2]*a1[2]);
    float b1[3] = {a1[0]/n1, a1[1]/n1, a1[2]/n1};
    float d = a2[0]*b1[0] + a2[1]*b1[1] + a2[2]*b1[2];
    float a2o[3] = {a2[0]-d*b1[0], a2[1]-d*b1[1], a2[2]-d*b1[2]};
    float n2 = sqrtf(a2o[0]*a2o[0] + a2o[1]*a2o[1] + a2o[2]*a2o[2]);
    float b2[3] = {a2o[0]/n2, a2o[1]/n2, a2o[2]/n2};
    float b3[3];
    cross3(b3, b1, b2);
    float R[9] = {b1[0], b2[0], b3[0],  b1[1], b2[1], b3[1],  b1[2], b2[2], b3[2]};
#pragma unroll
    for (int k = 0; k < 9; k++) sMRp[tid][k] = R[k];
    sMRp[tid][9] = p[0]; sMRp[tid][10] = p[1]; sMRp[tid][11] = p[2];
    if (tid < 7) {
#pragma unroll
      for (int rr = 0; rr < 3; rr++)
#pragma unroll
        for (int cc = 0; cc < 3; cc++) sIRp[tid][rr*3+cc] = R[cc*3+rr];
#pragma unroll
      for (int rr = 0; rr < 3; rr++)
        sIRp[tid][9+rr] = -(R[0*3+rr]*p[0] + R[1*3+rr]*p[1] + R[2*3+rr]*p[2]);
      const float* Ar = g_A + tid*6;
      float nw = sqrtf(Ar[0]*Ar[0] + Ar[1]*Ar[1] + Ar[2]*Ar[2]);
      sA2[tid][0] = Ar[0]/nw; sA2[tid][1] = Ar[1]/nw; sA2[tid][2] = Ar[2]/nw;
      sA2[tid][3] = Ar[3];    sA2[tid][4] = Ar[4];    sA2[tid][5] = Ar[5];
      sA2[tid][6] = 0.f;      sA2[tid][7] = 0.f;
      sG4[tid][0] = fabsf(g_G[tid*4+0]);
      sG4[tid][1] = fabsf(g_G[tid*4+1]);
      sG4[tid][2] = fabsf(g_G[tid*4+2]);
      sG4[tid][3] = fabsf(g_G[tid*4+3]);
    }
  }
  if (tid == 0) { sg[0] = g_grav[0]; sg[1] = g_grav[1]; sg[2] = g_grav[2]; }

  float q0 = 0.f, dq0 = 0.f, qs = 0.f, dqs = 0.f;
  float accq = 0.f, accd = 0.f, tau = 0.f;
  if (r < NDOF) {
    q0  = g_state[b*14 + r];
    dq0 = g_state[b*14 + 7 + r];
    tau = g_action[b*7 + r] * ACTION_RANGE;
    qs = q0; dqs = dq0;
  }
  WSYNC();

  // ---- per-lane register constants (loaded once, reused all 4 stages) ----
  float Areg[NDOF][6];
#pragma unroll
  for (int i = 0; i < NDOF; i++) {
    float4 a0 = *(const float4*)&sA2[i][0];
    float4 a1 = *(const float4*)&sA2[i][4];
    Areg[i][0] = a0.x; Areg[i][1] = a0.y; Areg[i][2] = a0.z;
    Areg[i][3] = a0.w; Areg[i][4] = a1.x; Areg[i][5] = a1.y;
  }
  float Aown[6] = {0.f,0.f,0.f,0.f,0.f,0.f};
  float IRl[9] = {0.f,0.f,0.f,0.f,0.f,0.f,0.f,0.f,0.f};
  float Ipl[3] = {0.f,0.f,0.f};
  if (r < NDOF) {
    float4 i0 = *(const float4*)&sIRp[r][0];
    float4 i1 = *(const float4*)&sIRp[r][4];
    float4 i2 = *(const float4*)&sIRp[r][8];
    IRl[0] = i0.x; IRl[1] = i0.y; IRl[2] = i0.z; IRl[3] = i0.w;
    IRl[4] = i1.x; IRl[5] = i1.y; IRl[6] = i1.z; IRl[7] = i1.w;
    IRl[8] = i2.x; Ipl[0] = i2.y; Ipl[1] = i2.z; Ipl[2] = i2.w;
    float4 a0 = *(const float4*)&sA2[r][0];
    float4 a1 = *(const float4*)&sA2[r][4];
    Aown[0] = a0.x; Aown[1] = a0.y; Aown[2] = a0.z;
    Aown[3] = a0.w; Aown[4] = a1.x; Aown[5] = a1.y;
  }
  float tauR[NDOF];
#pragma unroll
  for (int i = 0; i < NDOF; i++) tauR[i] = __shfl(tau, base + i, 64);
  const float gv0 = sg[0], gv1 = sg[1], gv2 = sg[2];

#pragma unroll 1
  for (int st = 0; st < 4; st++) {
    float bias_reg[NDOF];   // valid on lane r==7

    // ---- (A) adjoint of joint r, lanes r<7: T = exp(-q A) * M^-1 ----
    if (r < NDOF) {
      float Re[9], pe[3];
      exp_se3(Aown, -qs, Re, pe);
      float Tr9[9];
      mat3_mul(Tr9, Re, IRl);
      float Tp[3];
      mat3_vec(Tp, Re, Ipl);
      Tp[0] += pe[0]; Tp[1] += pe[1]; Tp[2] += pe[2];
      float* dst = &sRB[e][r*12];
      *(float4*)(dst + 0) = make_float4(Tr9[0], Tr9[1], Tr9[2], Tr9[3]);
      *(float4*)(dst + 4) = make_float4(Tr9[4], Tr9[5], Tr9[6], Tr9[7]);
      *(float4*)(dst + 8) = make_float4(Tr9[8], Tp[0], Tp[1], Tp[2]);
    }
    WSYNC();

    // ---- (BC) fused forward+backward sweep, ALL 8 lanes ----
    {
      float Rr[NDOF][9], Tph[NDOF][3];
      float Phw[NDOF][3], Phv[NDOF][3];
      float Pw[3] = {0.f,0.f,0.f}, Pv[3] = {0.f,0.f,0.f};
      float Qw[3] = {0.f,0.f,0.f}, Qv[3] = {0.f,0.f,0.f};
      if (r == 7) { Qv[0] = -gv0; Qv[1] = -gv1; Qv[2] = -gv2; }
#pragma unroll
      for (int i = 0; i < NDOF; i++) {
        const float* src = &sRB[e][i*12];
        float4 r0 = *(const float4*)(src + 0);
        float4 r1 = *(const float4*)(src + 4);
        float4 r2 = *(const float4*)(src + 8);
        Rr[i][0] = r0.x; Rr[i][1] = r0.y; Rr[i][2] = r0.z; Rr[i][3] = r0.w;
        Rr[i][4] = r1.x; Rr[i][5] = r1.y; Rr[i][6] = r1.z; Rr[i][7] = r1.w;
        Rr[i][8] = r2.x;
        Tph[i][0] = r2.y; Tph[i][1] = r2.z; Tph[i][2] = r2.w;
        float dqi = __shfl(dqs, base + i, 64);
        float Aw[3] = {Areg[i][0], Areg[i][1], Areg[i][2]};
        float Av[3] = {Areg[i][3], Areg[i][4], Areg[i][5]};
        // P: Vw' = R Pw (+cA*Aw); Vv' = Tp x (R Pw) + R Pv (+cA*Av)
        float Tw[3], t2[3], Tv[3];
        mat3_vec(Tw, Rr[i], Pw);
        mat3_vec(t2, Rr[i], Pv);
        cross3(Tv, Tph[i], Tw);
        float cA = (r == i) ? 1.f : ((r == 7) ? dqi : 0.f);
#pragma unroll
        for (int k = 0; k < 3; k++) {
          Pw[k] = Tw[k] + cA*Aw[k];
          Pv[k] = Tv[k] + t2[k] + cA*Av[k];
        }
        // Q = AdT*Q + dq_i * ad(P)A_i   (meaningful on lane 7 only)
        float Uw[3], u2[3], Uv[3];
        mat3_vec(Uw, Rr[i], Qw);
        mat3_vec(u2, Rr[i], Qv);
        cross3(Uv, Tph[i], Uw);
        float c1[3], c2[3], c3[3];
        cross3(c1, Pw, Aw);
        cross3(c2, Pv, Aw);
        cross3(c3, Pw, Av);
        float c8 = (r == 7) ? dqi : 0.f;
#pragma unroll
        for (int k = 0; k < 3; k++) {
          Qw[k] = Uw[k] + c8*c1[k];
          Qv[k] = Uv[k] + u2[k] + c8*(c2[k]+c3[k]);
        }
        if (r == 7) {
          float* qdst = &sQh[e][i*8];
          *(float4*)(qdst + 0) = make_float4(Qw[0], Qw[1], Qw[2], 0.f);
          *(float4*)(qdst + 4) = make_float4(Qv[0], Qv[1], Qv[2], 0.f);
        }
#pragma unroll
        for (int k = 0; k < 3; k++) { Phw[i][k] = Pw[k]; Phv[i][k] = Pv[k]; }
      }
      // backward: F' = AdT^T F; R^T(Fw + Fv x Tp) folds Bm^T in one matvec
      float Fw[3] = {0.f,0.f,0.f}, Fv[3] = {0.f,0.f,0.f};
#pragma unroll
      for (int i = NDOF-1; i >= 0; i--) {
        if (i < NDOF-1) {
          const int jn = i + 1;
          float cFT[3];
          cross3(cFT, Fv, Tph[jn]);
          float s0[3] = {Fw[0]+cFT[0], Fw[1]+cFT[1], Fw[2]+cFT[2]};
          float nw[3], nv[3];
          mat3T_vec(nw, Rr[jn], s0);
          mat3T_vec(nv, Rr[jn], Fv);
          Fw[0] = nw[0]; Fw[1] = nw[1]; Fw[2] = nw[2];
          Fv[0] = nv[0]; Fv[1] = nv[1]; Fv[2] = nv[2];
        }
        float4 g4 = *(const float4*)&sG4[i][0];
        float gx = g4.x, gy = g4.y, gz = g4.z, m_ = g4.w;
        float aw[3] = {gx*Phw[i][0], gy*Phw[i][1], gz*Phw[i][2]};
        float av[3] = {m_*Phv[i][0], m_*Phv[i][1], m_*Phv[i][2]};
        float4 d0 = *(const float4*)&sQh[e][i*8 + 0];
        float4 d1 = *(const float4*)&sQh[e][i*8 + 4];
        float GDw[3] = {gx*d0.x, gy*d0.y, gz*d0.z};
        float GDv[3] = {m_*d1.x, m_*d1.y, m_*d1.z};
        float x1[3], x2[3], x3[3];
        cross3(x1, Phw[i], aw);
        cross3(x2, Phv[i], av);
        cross3(x3, Phw[i], av);
        const bool l7 = (r == 7);
#pragma unroll
        for (int k = 0; k < 3; k++) {
          Fw[k] += l7 ? (GDw[k] + x1[k] + x2[k]) : aw[k];
          Fv[k] += l7 ? (GDv[k] + x3[k])         : av[k];
        }
        float val = Fw[0]*Areg[i][0] + Fw[1]*Areg[i][1] + Fw[2]*Areg[i][2]
                  + Fv[0]*Areg[i][3] + Fv[1]*Areg[i][4] + Fv[2]*Areg[i][5];
        if (r < NDOF && i >= r) MllL[(i*(i+1)/2 + r)*EP + e] = val;
        if (r == 7) bias_reg[i] = val;
      }
    }
    WSYNC();

    // ---- (D) Cholesky solve, lane r==7 (reciprocal-cached) ----
    if (r == 7) {
      float Lm[28], invd[NDOF];
#pragma unroll
      for (int idx = 0; idx < 28; idx++) Lm[idx] = MllL[idx*EP + e];
      float y[NDOF];
#pragma unroll
      for (int i = 0; i < NDOF; i++) y[i] = tauR[i] - bias_reg[i];
#pragma unroll
      for (int k = 0; k < NDOF; k++) {
        float d = Lm[k*(k+1)/2 + k];
#pragma unroll
        for (int m2 = 0; m2 < k; m2++) { float l = Lm[k*(k+1)/2 + m2]; d -= l*l; }
        d = sqrtf(d);
        Lm[k*(k+1)/2 + k] = d;
        float inv = 1.0f / d;
        invd[k] = inv;
#pragma unroll
        for (int i = k+1; i < NDOF; i++) {
          float s = Lm[i*(i+1)/2 + k];
#pragma unroll
          for (int m2 = 0; m2 < k; m2++) s -= Lm[i*(i+1)/2 + m2]*Lm[k*(k+1)/2 + m2];
          Lm[i*(i+1)/2 + k] = s * inv;
        }
      }
#pragma unroll
      for (int i = 0; i < NDOF; i++) {
        float s = y[i];
#pragma unroll
        for (int m2 = 0; m2 < i; m2++) s -= Lm[i*(i+1)/2 + m2]*y[m2];
        y[i] = s * invd[i];
      }
      float qac[NDOF];
#pragma unroll
      for (int i = NDOF-1; i >= 0; i--) {
        float s = y[i];
#pragma unroll
        for (int m2 = i+1; m2 < NDOF; m2++) s -= Lm[m2*(m2+1)/2 + i]*qac[m2];
        qac[i] = s * invd[i];
      }
#pragma unroll
      for (int i = 0; i < NDOF; i++) qaccL[i*EP + e] = qac[i];
    }
    WSYNC();

    // ---- (E) RK4 stage update, lanes r<7 ----
    if (r < NDOF) {
      float a = qaccL[r*EP + e];
      float w = (st == 0 || st == 3) ? 1.0f : 2.0f;
      accq += w * dqs;
      accd += w * a;
      if (st < 3) {
        float c = (st == 2) ? HSTEP : 0.5f*HSTEP;
        qs  = q0  + c * dqs;
        dqs = dq0 + c * a;
      }
    }
  }

  const float h6 = HSTEP / 6.0f;
  float qf = 0.f;
  if (r < NDOF) {
    qf = wrap_pi(q0 + h6*accq);
    float v  = dq0 + h6*accd;
    float dqf = fminf(fmaxf(v, -MAX_VEL), MAX_VEL);
    g_out_state[b*14 + r]     = qf;
    g_out_state[b*14 + 7 + r] = dqf;
  }

  // ---- FK: per-lane leaf + 3-step shuffle tree over the 8-lane group ----
  // lane r<7: T_r = M_r * exp(A_r, qf_r); lane 7: T_7 = M_7.
  // Product T_0 T_1 ... T_7 accumulates leftward; lane 0 ends with the full
  // chain (M_0 E_0)...(M_6 E_6) M_7; its p[0:2] is the EE position.
  float4 m0 = *(const float4*)&sMRp[r][0];
  float4 m1 = *(const float4*)&sMRp[r][4];
  float4 m2 = *(const float4*)&sMRp[r][8];
  float SR[9], Sp[3];
  if (r < NDOF) {
    float MR[9] = {m0.x, m0.y, m0.z, m0.w, m1.x, m1.y, m1.z, m1.w, m2.x};
    float Re[9], pe[3];
    exp_se3(Aown, qf, Re, pe);
    mat3_mul(SR, MR, Re);
    float t[3];
    mat3_vec(t, MR, pe);
    Sp[0] = t[0] + m2.y; Sp[1] = t[1] + m2.z; Sp[2] = t[2] + m2.w;
  } else {
    SR[0] = m0.x; SR[1] = m0.y; SR[2] = m0.z; SR[3] = m0.w;
    SR[4] = m1.x; SR[5] = m1.y; SR[6] = m1.z; SR[7] = m1.w;
    SR[8] = m2.x;
    Sp[0] = m2.y; Sp[1] = m2.z; Sp[2] = m2.w;
  }
#pragma unroll
  for (int off = 1; off < 8; off <<= 1) {
    const int partner = base + ((r + off) & 7);
    float PRm[9], Pp[3];
#pragma unroll
    for (int k = 0; k < 9; k++) PRm[k] = __shfl(SR[k], partner, 64);
#pragma unroll
    for (int k = 0; k < 3; k++) Pp[k] = __shfl(Sp[k], partner, 64);
    float NR[9], Np[3];
    mat3_mul(NR, SR, PRm);
    mat3_vec(Np, SR, Pp);
    Np[0] += Sp[0]; Np[1] += Sp[1]; Np[2] += Sp[2];
#pragma unroll
    for (int k = 0; k < 9; k++) SR[k] = NR[k];
    Sp[0] = Np[0]; Sp[1] = Np[1]; Sp[2] = Np[2];
  }
  if (r == 0) {
    g_out_ee[b*2 + 0] = Sp[0];
    g_out_ee[b*2 + 1] = Sp[1];
  }
}

extern "C" void kernel_launch(void* const* d_in, const int* in_sizes, int n_in,
                              void* d_out, int out_size, void* d_ws, size_t ws_size,
                              hipStream_t stream) {
  const float* state  = (const float*)d_in[0];  // (16384,14)
  const float* action = (const float*)d_in[1];  // (16384,7)
  const float* M      = (const float*)d_in[2];  // (8,4,4)
  const float* A      = (const float*)d_in[3];  // (7,6)
  const float* G      = (const float*)d_in[4];  // (7,4)
  const float* grav   = (const float*)d_in[5];  // (3,)
  float* out_state = (float*)d_out;                       // (16384,14)
  float* out_ee    = (float*)d_out + (size_t)BATCH * 14;  // (16384,2)

  arm_rk4_kernel<<<BATCH / EPB, BLOCK, 0, stream>>>(
      state, action, M, A, G, grav, out_state, out_ee);
}

// Round 2
// 106.302 us; speedup vs baseline: 1.0112x; 1.0112x over previous
//
#include <hip/hip_runtime.h>
#include <math.h>

#define BLOCK 64
#define BATCH 16384
#define EPB 8      // elements per block: 8 lanes per element
#define EP 9       // element-dim stride for scalar per-element LDS arrays
#define NDOF 7
#define ACTION_RANGE 50.0f
#define MAX_VEL 20.0f
#define HSTEP 0.1f

// BLOCK==64 -> exactly one wave per workgroup. DS ops from a single wave are
// processed in order by the LDS pipe, so cross-lane LDS communication needs
// no s_barrier — only a compiler fence to forbid reordering. (Validated: R14
// passed the harness with this scheme.)
#define WSYNC() asm volatile("" ::: "memory")

__device__ __forceinline__ void mat3_mul(float* C, const float* A, const float* B) {
#pragma unroll
  for (int r = 0; r < 3; r++) {
#pragma unroll
    for (int c = 0; c < 3; c++) {
      C[r*3+c] = A[r*3+0]*B[0*3+c] + A[r*3+1]*B[1*3+c] + A[r*3+2]*B[2*3+c];
    }
  }
}

__device__ __forceinline__ void mat3_vec(float* y, const float* A, const float* x) {
#pragma unroll
  for (int r = 0; r < 3; r++)
    y[r] = A[r*3+0]*x[0] + A[r*3+1]*x[1] + A[r*3+2]*x[2];
}

__device__ __forceinline__ void mat3T_vec(float* y, const float* A, const float* x) {
#pragma unroll
  for (int r = 0; r < 3; r++)
    y[r] = A[0*3+r]*x[0] + A[1*3+r]*x[1] + A[2*3+r]*x[2];
}

__device__ __forceinline__ void cross3(float* y, const float* a, const float* b) {
  y[0] = a[1]*b[2] - a[2]*b[1];
  y[1] = a[2]*b[0] - a[0]*b[2];
  y[2] = a[0]*b[1] - a[1]*b[0];
}

// Rodrigues-direct for UNIT axis w (W^2 = ww^T - I):
//   R = cI + sW + (1-c)ww^T ;  G v with G = sI + (1-c)W + (th-s)ww^T
__device__ __forceinline__ void exp_se3(const float* A6, float th, float* R, float* p) {
  float w0 = A6[0], w1 = A6[1], w2 = A6[2];
  float s = __sinf(th);
  float c = __cosf(th);
  float omc = 1.0f - c, tms = th - s;
  float p00 = w0*w0, p01 = w0*w1, p02 = w0*w2;
  float p11 = w1*w1, p12 = w1*w2, p22 = w2*w2;
  R[0] = c + omc*p00;       R[1] = omc*p01 - s*w2;   R[2] = omc*p02 + s*w1;
  R[3] = omc*p01 + s*w2;    R[4] = c + omc*p11;      R[5] = omc*p12 - s*w0;
  R[6] = omc*p02 - s*w1;    R[7] = omc*p12 + s*w0;   R[8] = c + omc*p22;
  float G0 = s + tms*p00,    G1 = tms*p01 - omc*w2,  G2 = tms*p02 + omc*w1;
  float G3 = tms*p01 + omc*w2, G4 = s + tms*p11,     G5 = tms*p12 - omc*w0;
  float G6 = tms*p02 - omc*w1, G7 = tms*p12 + omc*w0, G8 = s + tms*p22;
  p[0] = G0*A6[3] + G1*A6[4] + G2*A6[5];
  p[1] = G3*A6[3] + G4*A6[4] + G5*A6[5];
  p[2] = G6*A6[3] + G7*A6[4] + G8*A6[5];
}

__device__ __forceinline__ float wrap_pi(float x) {
  const float PI_F   = 3.14159265358979323846f;
  const float TWO_PI = 6.28318530717958647692f;
  float a = x + PI_F;
  float r = a - floorf(a * (1.0f / TWO_PI)) * TWO_PI;
  return r - PI_F;
}

// R15 = R14 minus the register-cache that broke the occupancy tier:
//  - __launch_bounds__(64,4): cap VGPR at 128 -> 4-waves/SIMD capacity tier
//    restored (R14's 184 VGPR -> capacity 2/SIMD, zero placement slack,
//    measured occupancy 14.4% -> 9.3% and dur 41.5 -> 51.2us).
//  - R/Tp and A are re-read from LDS in the backward pass (broadcast-pattern
//    ds_read_b128, conflict-free) instead of being held live across the
//    whole sweep. IR/Ip read per stage.
//  - Keeps from R14: Bm eliminated algebraically (12 floats/joint), float4
//    bank-skewed LDS layout (stride 84/60 words), barrier-free wave-sync,
//    FK as full-lane shuffle tree, lane-7 tau via LDS.
__global__ __launch_bounds__(BLOCK, 4) void arm_rk4_kernel(
    const float* __restrict__ g_state, const float* __restrict__ g_action,
    const float* __restrict__ g_M, const float* __restrict__ g_A,
    const float* __restrict__ g_G, const float* __restrict__ g_grav,
    float* __restrict__ g_out_state, float* __restrict__ g_out_ee)
{
  __shared__ alignas(16) float sRB[8][84];   // joint i at [e][i*12]: R[0..8], Tp[3]
  __shared__ alignas(16) float sQh[8][60];   // joint i at [e][i*8]: Qw[3],pad,Qv[3],pad
  __shared__ alignas(16) float sIRp[7][12];  // M_i^-1: R^T[9], (-R^T p)[3]
  __shared__ alignas(16) float sMRp[8][12];  // M_i: R[9], p[3]
  __shared__ alignas(16) float sA2[7][8];    // w[3], v[3], pad2
  __shared__ alignas(16) float sG4[7][4];
  __shared__ float sg[4];
  __shared__ float tauL[NDOF*EP];
  __shared__ float qaccL[NDOF*EP];
  __shared__ float MllL[28*EP];

  const int tid  = threadIdx.x;
  const int e    = tid >> 3;      // element slot 0..7
  const int r    = tid & 7;       // role 0..7
  const int base = tid & 0x38;    // first lane of this element group
  const int b    = blockIdx.x * EPB + e;

  if (tid < 8) {
    const float* Mi = g_M + tid*16;
    float a1[3] = {Mi[0], Mi[4], Mi[8]};
    float a2[3] = {Mi[1], Mi[5], Mi[9]};
    float p[3]  = {Mi[3], Mi[7], Mi[11]};
    float n1 = sqrtf(a1[0]*a1[0] + a1[1]*a1[1] + a1[2]*a1[2]);
    float b1[3] = {a1[0]/n1, a1[1]/n1, a1[2]/n1};
    float d = a2[0]*b1[0] + a2[1]*b1[1] + a2[2]*b1[2];
    float a2o[3] = {a2[0]-d*b1[0], a2[1]-d*b1[1], a2[2]-d*b1[2]};
    float n2 = sqrtf(a2o[0]*a2o[0] + a2o[1]*a2o[1] + a2o[2]*a2o[2]);
    float b2[3] = {a2o[0]/n2, a2o[1]/n2, a2o[2]/n2};
    float b3[3];
    cross3(b3, b1, b2);
    float R[9] = {b1[0], b2[0], b3[0],  b1[1], b2[1], b3[1],  b1[2], b2[2], b3[2]};
#pragma unroll
    for (int k = 0; k < 9; k++) sMRp[tid][k] = R[k];
    sMRp[tid][9] = p[0]; sMRp[tid][10] = p[1]; sMRp[tid][11] = p[2];
    if (tid < 7) {
#pragma unroll
      for (int rr = 0; rr < 3; rr++)
#pragma unroll
        for (int cc = 0; cc < 3; cc++) sIRp[tid][rr*3+cc] = R[cc*3+rr];
#pragma unroll
      for (int rr = 0; rr < 3; rr++)
        sIRp[tid][9+rr] = -(R[0*3+rr]*p[0] + R[1*3+rr]*p[1] + R[2*3+rr]*p[2]);
      const float* Ar = g_A + tid*6;
      float nw = sqrtf(Ar[0]*Ar[0] + Ar[1]*Ar[1] + Ar[2]*Ar[2]);
      sA2[tid][0] = Ar[0]/nw; sA2[tid][1] = Ar[1]/nw; sA2[tid][2] = Ar[2]/nw;
      sA2[tid][3] = Ar[3];    sA2[tid][4] = Ar[4];    sA2[tid][5] = Ar[5];
      sA2[tid][6] = 0.f;      sA2[tid][7] = 0.f;
      sG4[tid][0] = fabsf(g_G[tid*4+0]);
      sG4[tid][1] = fabsf(g_G[tid*4+1]);
      sG4[tid][2] = fabsf(g_G[tid*4+2]);
      sG4[tid][3] = fabsf(g_G[tid*4+3]);
    }
  }
  if (tid == 0) { sg[0] = g_grav[0]; sg[1] = g_grav[1]; sg[2] = g_grav[2]; }

  float q0 = 0.f, dq0 = 0.f, qs = 0.f, dqs = 0.f;
  float accq = 0.f, accd = 0.f;
  if (r < NDOF) {
    q0  = g_state[b*14 + r];
    dq0 = g_state[b*14 + 7 + r];
    float tau = g_action[b*7 + r] * ACTION_RANGE;
    qs = q0; dqs = dq0;
    tauL[r*EP + e] = tau;
  }
  WSYNC();

  // own-joint axis kept in registers (6 regs, used every stage + FK tail)
  float Aown[6] = {0.f,0.f,0.f,0.f,0.f,0.f};
  if (r < NDOF) {
    float4 a0 = *(const float4*)&sA2[r][0];
    float4 a1 = *(const float4*)&sA2[r][4];
    Aown[0] = a0.x; Aown[1] = a0.y; Aown[2] = a0.z;
    Aown[3] = a0.w; Aown[4] = a1.x; Aown[5] = a1.y;
  }
  const float gv0 = sg[0], gv1 = sg[1], gv2 = sg[2];

#pragma unroll 1
  for (int st = 0; st < 4; st++) {
    float bias_reg[NDOF];   // valid on lane r==7

    // ---- (A) adjoint of joint r, lanes r<7: T = exp(-q A) * M^-1 ----
    if (r < NDOF) {
      float4 i0 = *(const float4*)&sIRp[r][0];
      float4 i1 = *(const float4*)&sIRp[r][4];
      float4 i2 = *(const float4*)&sIRp[r][8];
      float IRl[9] = {i0.x, i0.y, i0.z, i0.w, i1.x, i1.y, i1.z, i1.w, i2.x};
      float Ipl[3] = {i2.y, i2.z, i2.w};
      float Re[9], pe[3];
      exp_se3(Aown, -qs, Re, pe);
      float Tr9[9];
      mat3_mul(Tr9, Re, IRl);
      float Tp[3];
      mat3_vec(Tp, Re, Ipl);
      Tp[0] += pe[0]; Tp[1] += pe[1]; Tp[2] += pe[2];
      float* dst = &sRB[e][r*12];
      *(float4*)(dst + 0) = make_float4(Tr9[0], Tr9[1], Tr9[2], Tr9[3]);
      *(float4*)(dst + 4) = make_float4(Tr9[4], Tr9[5], Tr9[6], Tr9[7]);
      *(float4*)(dst + 8) = make_float4(Tr9[8], Tp[0], Tp[1], Tp[2]);
    }
    WSYNC();

    // ---- (BC) fused forward+backward sweep, ALL 8 lanes ----
    {
      float Phw[NDOF][3], Phv[NDOF][3];
      float Pw[3] = {0.f,0.f,0.f}, Pv[3] = {0.f,0.f,0.f};
      float Qw[3] = {0.f,0.f,0.f}, Qv[3] = {0.f,0.f,0.f};
      if (r == 7) { Qv[0] = -gv0; Qv[1] = -gv1; Qv[2] = -gv2; }
#pragma unroll
      for (int i = 0; i < NDOF; i++) {
        const float* src = &sRB[e][i*12];
        float4 r0 = *(const float4*)(src + 0);
        float4 r1 = *(const float4*)(src + 4);
        float4 r2 = *(const float4*)(src + 8);
        float Rm[9] = {r0.x, r0.y, r0.z, r0.w, r1.x, r1.y, r1.z, r1.w, r2.x};
        float Tpl[3] = {r2.y, r2.z, r2.w};
        float4 a0 = *(const float4*)&sA2[i][0];
        float4 a1 = *(const float4*)&sA2[i][4];
        float Aw[3] = {a0.x, a0.y, a0.z};
        float Av[3] = {a0.w, a1.x, a1.y};
        float dqi = __shfl(dqs, base + i, 64);
        // P: Pw' = R Pw (+cA*Aw); Pv' = Tp x (R Pw) + R Pv (+cA*Av)
        float Tw[3], t2[3], Tv[3];
        mat3_vec(Tw, Rm, Pw);
        mat3_vec(t2, Rm, Pv);
        cross3(Tv, Tpl, Tw);
        float cA = (r == i) ? 1.f : ((r == 7) ? dqi : 0.f);
#pragma unroll
        for (int k = 0; k < 3; k++) {
          Pw[k] = Tw[k] + cA*Aw[k];
          Pv[k] = Tv[k] + t2[k] + cA*Av[k];
        }
        // Q = AdT*Q + dq_i * ad(P)A_i   (meaningful on lane 7 only)
        float Uw[3], u2[3], Uv[3];
        mat3_vec(Uw, Rm, Qw);
        mat3_vec(u2, Rm, Qv);
        cross3(Uv, Tpl, Uw);
        float c1[3], c2[3], c3[3];
        cross3(c1, Pw, Aw);
        cross3(c2, Pv, Aw);
        cross3(c3, Pw, Av);
        float c8 = (r == 7) ? dqi : 0.f;
#pragma unroll
        for (int k = 0; k < 3; k++) {
          Qw[k] = Uw[k] + c8*c1[k];
          Qv[k] = Uv[k] + u2[k] + c8*(c2[k]+c3[k]);
        }
        if (r == 7) {
          float* qdst = &sQh[e][i*8];
          *(float4*)(qdst + 0) = make_float4(Qw[0], Qw[1], Qw[2], 0.f);
          *(float4*)(qdst + 4) = make_float4(Qv[0], Qv[1], Qv[2], 0.f);
        }
#pragma unroll
        for (int k = 0; k < 3; k++) { Phw[i][k] = Pw[k]; Phv[i][k] = Pv[k]; }
      }
      // backward: F' = AdT^T F via R^T(Fw + Fv x Tp), R/Tp re-read from LDS
      float Fw[3] = {0.f,0.f,0.f}, Fv[3] = {0.f,0.f,0.f};
#pragma unroll
      for (int i = NDOF-1; i >= 0; i--) {
        if (i < NDOF-1) {
          const int jn = i + 1;
          const float* src = &sRB[e][jn*12];
          float4 r0 = *(const float4*)(src + 0);
          float4 r1 = *(const float4*)(src + 4);
          float4 r2 = *(const float4*)(src + 8);
          float Rm[9] = {r0.x, r0.y, r0.z, r0.w, r1.x, r1.y, r1.z, r1.w, r2.x};
          float Tpl[3] = {r2.y, r2.z, r2.w};
          float cFT[3];
          cross3(cFT, Fv, Tpl);
          float s0[3] = {Fw[0]+cFT[0], Fw[1]+cFT[1], Fw[2]+cFT[2]};
          float nw[3], nv[3];
          mat3T_vec(nw, Rm, s0);
          mat3T_vec(nv, Rm, Fv);
          Fw[0] = nw[0]; Fw[1] = nw[1]; Fw[2] = nw[2];
          Fv[0] = nv[0]; Fv[1] = nv[1]; Fv[2] = nv[2];
        }
        float4 g4 = *(const float4*)&sG4[i][0];
        float gx = g4.x, gy = g4.y, gz = g4.z, m_ = g4.w;
        float aw[3] = {gx*Phw[i][0], gy*Phw[i][1], gz*Phw[i][2]};
        float av[3] = {m_*Phv[i][0], m_*Phv[i][1], m_*Phv[i][2]};
        float4 d0 = *(const float4*)&sQh[e][i*8 + 0];
        float4 d1 = *(const float4*)&sQh[e][i*8 + 4];
        float GDw[3] = {gx*d0.x, gy*d0.y, gz*d0.z};
        float GDv[3] = {m_*d1.x, m_*d1.y, m_*d1.z};
        float x1[3], x2[3], x3[3];
        cross3(x1, Phw[i], aw);
        cross3(x2, Phv[i], av);
        cross3(x3, Phw[i], av);
        const bool l7 = (r == 7);
#pragma unroll
        for (int k = 0; k < 3; k++) {
          Fw[k] += l7 ? (GDw[k] + x1[k] + x2[k]) : aw[k];
          Fv[k] += l7 ? (GDv[k] + x3[k])         : av[k];
        }
        float4 a0 = *(const float4*)&sA2[i][0];
        float4 a1 = *(const float4*)&sA2[i][4];
        float val = Fw[0]*a0.x + Fw[1]*a0.y + Fw[2]*a0.z
                  + Fv[0]*a0.w + Fv[1]*a1.x + Fv[2]*a1.y;
        if (r < NDOF && i >= r) MllL[(i*(i+1)/2 + r)*EP + e] = val;
        if (r == 7) bias_reg[i] = val;
      }
    }
    WSYNC();

    // ---- (D) Cholesky solve, lane r==7 (reciprocal-cached) ----
    if (r == 7) {
      float Lm[28], invd[NDOF];
#pragma unroll
      for (int idx = 0; idx < 28; idx++) Lm[idx] = MllL[idx*EP + e];
      float y[NDOF];
#pragma unroll
      for (int i = 0; i < NDOF; i++) y[i] = tauL[i*EP + e] - bias_reg[i];
#pragma unroll
      for (int k = 0; k < NDOF; k++) {
        float d = Lm[k*(k+1)/2 + k];
#pragma unroll
        for (int m2 = 0; m2 < k; m2++) { float l = Lm[k*(k+1)/2 + m2]; d -= l*l; }
        d = sqrtf(d);
        Lm[k*(k+1)/2 + k] = d;
        float inv = 1.0f / d;
        invd[k] = inv;
#pragma unroll
        for (int i = k+1; i < NDOF; i++) {
          float s = Lm[i*(i+1)/2 + k];
#pragma unroll
          for (int m2 = 0; m2 < k; m2++) s -= Lm[i*(i+1)/2 + m2]*Lm[k*(k+1)/2 + m2];
          Lm[i*(i+1)/2 + k] = s * inv;
        }
      }
#pragma unroll
      for (int i = 0; i < NDOF; i++) {
        float s = y[i];
#pragma unroll
        for (int m2 = 0; m2 < i; m2++) s -= Lm[i*(i+1)/2 + m2]*y[m2];
        y[i] = s * invd[i];
      }
      float qac[NDOF];
#pragma unroll
      for (int i = NDOF-1; i >= 0; i--) {
        float s = y[i];
#pragma unroll
        for (int m2 = i+1; m2 < NDOF; m2++) s -= Lm[m2*(m2+1)/2 + i]*qac[m2];
        qac[i] = s * invd[i];
      }
#pragma unroll
      for (int i = 0; i < NDOF; i++) qaccL[i*EP + e] = qac[i];
    }
    WSYNC();

    // ---- (E) RK4 stage update, lanes r<7 ----
    if (r < NDOF) {
      float a = qaccL[r*EP + e];
      float w = (st == 0 || st == 3) ? 1.0f : 2.0f;
      accq += w * dqs;
      accd += w * a;
      if (st < 3) {
        float c = (st == 2) ? HSTEP : 0.5f*HSTEP;
        qs  = q0  + c * dqs;
        dqs = dq0 + c * a;
      }
    }
  }

  const float h6 = HSTEP / 6.0f;
  float qf = 0.f;
  if (r < NDOF) {
    qf = wrap_pi(q0 + h6*accq);
    float v  = dq0 + h6*accd;
    float dqf = fminf(fmaxf(v, -MAX_VEL), MAX_VEL);
    g_out_state[b*14 + r]     = qf;
    g_out_state[b*14 + 7 + r] = dqf;
  }

  // ---- FK: per-lane leaf + 3-step shuffle tree over the 8-lane group ----
  // lane r<7: T_r = M_r * exp(A_r, qf_r); lane 7: T_7 = M_7.
  // Leftward product: lane 0 ends with (M_0 E_0)...(M_6 E_6) M_7.
  float4 m0 = *(const float4*)&sMRp[r][0];
  float4 m1 = *(const float4*)&sMRp[r][4];
  float4 m2 = *(const float4*)&sMRp[r][8];
  float SR[9], Sp[3];
  if (r < NDOF) {
    float MR[9] = {m0.x, m0.y, m0.z, m0.w, m1.x, m1.y, m1.z, m1.w, m2.x};
    float Re[9], pe[3];
    exp_se3(Aown, qf, Re, pe);
    mat3_mul(SR, MR, Re);
    float t[3];
    mat3_vec(t, MR, pe);
    Sp[0] = t[0] + m2.y; Sp[1] = t[1] + m2.z; Sp[2] = t[2] + m2.w;
  } else {
    SR[0] = m0.x; SR[1] = m0.y; SR[2] = m0.z; SR[3] = m0.w;
    SR[4] = m1.x; SR[5] = m1.y; SR[6] = m1.z; SR[7] = m1.w;
    SR[8] = m2.x;
    Sp[0] = m2.y; Sp[1] = m2.z; Sp[2] = m2.w;
  }
#pragma unroll
  for (int off = 1; off < 8; off <<= 1) {
    const int partner = base + ((r + off) & 7);
    float PRm[9], Pp[3];
#pragma unroll
    for (int k = 0; k < 9; k++) PRm[k] = __shfl(SR[k], partner, 64);
#pragma unroll
    for (int k = 0; k < 3; k++) Pp[k] = __shfl(Sp[k], partner, 64);
    float NR[9], Np[3];
    mat3_mul(NR, SR, PRm);
    mat3_vec(Np, SR, Pp);
    Np[0] += Sp[0]; Np[1] += Sp[1]; Np[2] += Sp[2];
#pragma unroll
    for (int k = 0; k < 9; k++) SR[k] = NR[k];
    Sp[0] = Np[0]; Sp[1] = Np[1]; Sp[2] = Np[2];
  }
  if (r == 0) {
    g_out_ee[b*2 + 0] = Sp[0];
    g_out_ee[b*2 + 1] = Sp[1];
  }
}

extern "C" void kernel_launch(void* const* d_in, const int* in_sizes, int n_in,
                              void* d_out, int out_size, void* d_ws, size_t ws_size,
                              hipStream_t stream) {
  const float* state  = (const float*)d_in[0];  // (16384,14)
  const float* action = (const float*)d_in[1];  // (16384,7)
  const float* M      = (const float*)d_in[2];  // (8,4,4)
  const float* A      = (const float*)d_in[3];  // (7,6)
  const float* G      = (const float*)d_in[4];  // (7,4)
  const float* grav   = (const float*)d_in[5];  // (3,)
  float* out_state = (float*)d_out;                       // (16384,14)
  float* out_ee    = (float*)d_out + (size_t)BATCH * 14;  // (16384,2)

  arm_rk4_kernel<<<BATCH / EPB, BLOCK, 0, stream>>>(
      state, action, M, A, G, grav, out_state, out_ee);
}

// Round 3
// 104.540 us; speedup vs baseline: 1.0282x; 1.0169x over previous
//
#include <hip/hip_runtime.h>
#include <math.h>

#define BLOCK 64
#define BATCH 16384
#define EPB 8      // elements per block: 8 lanes per element
#define EP 9       // element-dim stride for scalar per-element LDS arrays
#define NDOF 7
#define ACTION_RANGE 50.0f
#define MAX_VEL 20.0f
#define HSTEP 0.1f

// BLOCK==64 -> exactly one wave per workgroup. DS ops from a single wave are
// processed in order by the LDS pipe, so cross-lane LDS communication needs
// no s_barrier — only a compiler fence to forbid reordering. (Validated:
// R14/R15 passed the harness with this scheme.)
#define WSYNC() asm volatile("" ::: "memory")
// Pin program order at loop-iteration boundaries: stops the scheduler from
// prefetching several joints' float4 LDS reads ahead (the R14 184-VGPR
// balloon). 4 waves/SIMD TLP hides the exposed per-iteration ds_read latency.
#define SCHED_FENCE() __builtin_amdgcn_sched_barrier(0)

__device__ __forceinline__ void mat3_mul(float* C, const float* A, const float* B) {
#pragma unroll
  for (int r = 0; r < 3; r++) {
#pragma unroll
    for (int c = 0; c < 3; c++) {
      C[r*3+c] = A[r*3+0]*B[0*3+c] + A[r*3+1]*B[1*3+c] + A[r*3+2]*B[2*3+c];
    }
  }
}

__device__ __forceinline__ void mat3_vec(float* y, const float* A, const float* x) {
#pragma unroll
  for (int r = 0; r < 3; r++)
    y[r] = A[r*3+0]*x[0] + A[r*3+1]*x[1] + A[r*3+2]*x[2];
}

__device__ __forceinline__ void mat3T_vec(float* y, const float* A, const float* x) {
#pragma unroll
  for (int r = 0; r < 3; r++)
    y[r] = A[0*3+r]*x[0] + A[1*3+r]*x[1] + A[2*3+r]*x[2];
}

__device__ __forceinline__ void cross3(float* y, const float* a, const float* b) {
  y[0] = a[1]*b[2] - a[2]*b[1];
  y[1] = a[2]*b[0] - a[0]*b[2];
  y[2] = a[0]*b[1] - a[1]*b[0];
}

// Rodrigues-direct for UNIT axis w (W^2 = ww^T - I):
//   R = cI + sW + (1-c)ww^T ;  G v with G = sI + (1-c)W + (th-s)ww^T
__device__ __forceinline__ void exp_se3(const float* A6, float th, float* R, float* p) {
  float w0 = A6[0], w1 = A6[1], w2 = A6[2];
  float s = __sinf(th);
  float c = __cosf(th);
  float omc = 1.0f - c, tms = th - s;
  float p00 = w0*w0, p01 = w0*w1, p02 = w0*w2;
  float p11 = w1*w1, p12 = w1*w2, p22 = w2*w2;
  R[0] = c + omc*p00;       R[1] = omc*p01 - s*w2;   R[2] = omc*p02 + s*w1;
  R[3] = omc*p01 + s*w2;    R[4] = c + omc*p11;      R[5] = omc*p12 - s*w0;
  R[6] = omc*p02 - s*w1;    R[7] = omc*p12 + s*w0;   R[8] = c + omc*p22;
  float G0 = s + tms*p00,    G1 = tms*p01 - omc*w2,  G2 = tms*p02 + omc*w1;
  float G3 = tms*p01 + omc*w2, G4 = s + tms*p11,     G5 = tms*p12 - omc*w0;
  float G6 = tms*p02 - omc*w1, G7 = tms*p12 + omc*w0, G8 = s + tms*p22;
  p[0] = G0*A6[3] + G1*A6[4] + G2*A6[5];
  p[1] = G3*A6[3] + G4*A6[4] + G5*A6[5];
  p[2] = G6*A6[3] + G7*A6[4] + G8*A6[5];
}

__device__ __forceinline__ float wrap_pi(float x) {
  const float PI_F   = 3.14159265358979323846f;
  const float TWO_PI = 6.28318530717958647692f;
  float a = x + PI_F;
  float r = a - floorf(a * (1.0f / TWO_PI)) * TWO_PI;
  return r - PI_F;
}

// R16 = R15 with register-pressure control instead of allocator guessing:
//  - amdgpu_waves_per_eu(4,4): HARD 128-VGPR budget. R15's launch_bounds(64,4)
//    was a MINIMUM; the allocator chased 8 waves/EU -> 64 VGPR + 29MB of
//    scratch spill (measured WRITE_SIZE 20MB). min=max=4 removes that.
//  - sched_barrier(0) per joint iteration: stops the unrolled float4 loop
//    from prefetching joints ahead (R14's 184-VGPR balloon).
//  - bias column moved to LDS (biasL): -7 persistent regs on the peak path.
//  - Everything else identical to R15 (Bm-free adjoint, float4 bank-skewed
//    LDS, barrier-free wave sync, FK shuffle tree).
__global__ __launch_bounds__(BLOCK)
__attribute__((amdgpu_waves_per_eu(4, 4)))
void arm_rk4_kernel(
    const float* __restrict__ g_state, const float* __restrict__ g_action,
    const float* __restrict__ g_M, const float* __restrict__ g_A,
    const float* __restrict__ g_G, const float* __restrict__ g_grav,
    float* __restrict__ g_out_state, float* __restrict__ g_out_ee)
{
  __shared__ alignas(16) float sRB[8][84];   // joint i at [e][i*12]: R[0..8], Tp[3]
  __shared__ alignas(16) float sQh[8][60];   // joint i at [e][i*8]: Qw[3],pad,Qv[3],pad
  __shared__ alignas(16) float sIRp[7][12];  // M_i^-1: R^T[9], (-R^T p)[3]
  __shared__ alignas(16) float sMRp[8][12];  // M_i: R[9], p[3]
  __shared__ alignas(16) float sA2[7][8];    // w[3], v[3], pad2
  __shared__ alignas(16) float sG4[7][4];
  __shared__ float sg[4];
  __shared__ float tauL[NDOF*EP];
  __shared__ float qaccL[NDOF*EP];
  __shared__ float biasL[NDOF*EP];
  __shared__ float MllL[28*EP];

  const int tid  = threadIdx.x;
  const int e    = tid >> 3;      // element slot 0..7
  const int r    = tid & 7;       // role 0..7
  const int base = tid & 0x38;    // first lane of this element group
  const int b    = blockIdx.x * EPB + e;

  if (tid < 8) {
    const float* Mi = g_M + tid*16;
    float a1[3] = {Mi[0], Mi[4], Mi[8]};
    float a2[3] = {Mi[1], Mi[5], Mi[9]};
    float p[3]  = {Mi[3], Mi[7], Mi[11]};
    float n1 = sqrtf(a1[0]*a1[0] + a1[1]*a1[1] + a1[2]*a1[2]);
    float b1[3] = {a1[0]/n1, a1[1]/n1, a1[2]/n1};
    float d = a2[0]*b1[0] + a2[1]*b1[1] + a2[2]*b1[2];
    float a2o[3] = {a2[0]-d*b1[0], a2[1]-d*b1[1], a2[2]-d*b1[2]};
    float n2 = sqrtf(a2o[0]*a2o[0] + a2o[1]*a2o[1] + a2o[2]*a2o[2]);
    float b2[3] = {a2o[0]/n2, a2o[1]/n2, a2o[2]/n2};
    float b3[3];
    cross3(b3, b1, b2);
    float R[9] = {b1[0], b2[0], b3[0],  b1[1], b2[1], b3[1],  b1[2], b2[2], b3[2]};
#pragma unroll
    for (int k = 0; k < 9; k++) sMRp[tid][k] = R[k];
    sMRp[tid][9] = p[0]; sMRp[tid][10] = p[1]; sMRp[tid][11] = p[2];
    if (tid < 7) {
#pragma unroll
      for (int rr = 0; rr < 3; rr++)
#pragma unroll
        for (int cc = 0; cc < 3; cc++) sIRp[tid][rr*3+cc] = R[cc*3+rr];
#pragma unroll
      for (int rr = 0; rr < 3; rr++)
        sIRp[tid][9+rr] = -(R[0*3+rr]*p[0] + R[1*3+rr]*p[1] + R[2*3+rr]*p[2]);
      const float* Ar = g_A + tid*6;
      float nw = sqrtf(Ar[0]*Ar[0] + Ar[1]*Ar[1] + Ar[2]*Ar[2]);
      sA2[tid][0] = Ar[0]/nw; sA2[tid][1] = Ar[1]/nw; sA2[tid][2] = Ar[2]/nw;
      sA2[tid][3] = Ar[3];    sA2[tid][4] = Ar[4];    sA2[tid][5] = Ar[5];
      sA2[tid][6] = 0.f;      sA2[tid][7] = 0.f;
      sG4[tid][0] = fabsf(g_G[tid*4+0]);
      sG4[tid][1] = fabsf(g_G[tid*4+1]);
      sG4[tid][2] = fabsf(g_G[tid*4+2]);
      sG4[tid][3] = fabsf(g_G[tid*4+3]);
    }
  }
  if (tid == 0) { sg[0] = g_grav[0]; sg[1] = g_grav[1]; sg[2] = g_grav[2]; }

  float q0 = 0.f, dq0 = 0.f, qs = 0.f, dqs = 0.f;
  float accq = 0.f, accd = 0.f;
  if (r < NDOF) {
    q0  = g_state[b*14 + r];
    dq0 = g_state[b*14 + 7 + r];
    float tau = g_action[b*7 + r] * ACTION_RANGE;
    qs = q0; dqs = dq0;
    tauL[r*EP + e] = tau;
  }
  WSYNC();

  // own-joint axis kept in registers (6 regs, used every stage + FK tail)
  float Aown[6] = {0.f,0.f,0.f,0.f,0.f,0.f};
  if (r < NDOF) {
    float4 a0 = *(const float4*)&sA2[r][0];
    float4 a1 = *(const float4*)&sA2[r][4];
    Aown[0] = a0.x; Aown[1] = a0.y; Aown[2] = a0.z;
    Aown[3] = a0.w; Aown[4] = a1.x; Aown[5] = a1.y;
  }
  const float gv0 = sg[0], gv1 = sg[1], gv2 = sg[2];

#pragma unroll 1
  for (int st = 0; st < 4; st++) {
    // ---- (A) adjoint of joint r, lanes r<7: T = exp(-q A) * M^-1 ----
    if (r < NDOF) {
      float4 i0 = *(const float4*)&sIRp[r][0];
      float4 i1 = *(const float4*)&sIRp[r][4];
      float4 i2 = *(const float4*)&sIRp[r][8];
      float IRl[9] = {i0.x, i0.y, i0.z, i0.w, i1.x, i1.y, i1.z, i1.w, i2.x};
      float Ipl[3] = {i2.y, i2.z, i2.w};
      float Re[9], pe[3];
      exp_se3(Aown, -qs, Re, pe);
      float Tr9[9];
      mat3_mul(Tr9, Re, IRl);
      float Tp[3];
      mat3_vec(Tp, Re, Ipl);
      Tp[0] += pe[0]; Tp[1] += pe[1]; Tp[2] += pe[2];
      float* dst = &sRB[e][r*12];
      *(float4*)(dst + 0) = make_float4(Tr9[0], Tr9[1], Tr9[2], Tr9[3]);
      *(float4*)(dst + 4) = make_float4(Tr9[4], Tr9[5], Tr9[6], Tr9[7]);
      *(float4*)(dst + 8) = make_float4(Tr9[8], Tp[0], Tp[1], Tp[2]);
    }
    WSYNC();
    SCHED_FENCE();

    // ---- (BC) fused forward+backward sweep, ALL 8 lanes ----
    {
      float Phw[NDOF][3], Phv[NDOF][3];
      float Pw[3] = {0.f,0.f,0.f}, Pv[3] = {0.f,0.f,0.f};
      float Qw[3] = {0.f,0.f,0.f}, Qv[3] = {0.f,0.f,0.f};
      if (r == 7) { Qv[0] = -gv0; Qv[1] = -gv1; Qv[2] = -gv2; }
#pragma unroll
      for (int i = 0; i < NDOF; i++) {
        const float* src = &sRB[e][i*12];
        float4 r0 = *(const float4*)(src + 0);
        float4 r1 = *(const float4*)(src + 4);
        float4 r2 = *(const float4*)(src + 8);
        float Rm[9] = {r0.x, r0.y, r0.z, r0.w, r1.x, r1.y, r1.z, r1.w, r2.x};
        float Tpl[3] = {r2.y, r2.z, r2.w};
        float4 a0 = *(const float4*)&sA2[i][0];
        float4 a1 = *(const float4*)&sA2[i][4];
        float Aw[3] = {a0.x, a0.y, a0.z};
        float Av[3] = {a0.w, a1.x, a1.y};
        float dqi = __shfl(dqs, base + i, 64);
        // P: Pw' = R Pw (+cA*Aw); Pv' = Tp x (R Pw) + R Pv (+cA*Av)
        float Tw[3], t2[3], Tv[3];
        mat3_vec(Tw, Rm, Pw);
        mat3_vec(t2, Rm, Pv);
        cross3(Tv, Tpl, Tw);
        float cA = (r == i) ? 1.f : ((r == 7) ? dqi : 0.f);
#pragma unroll
        for (int k = 0; k < 3; k++) {
          Pw[k] = Tw[k] + cA*Aw[k];
          Pv[k] = Tv[k] + t2[k] + cA*Av[k];
        }
        // Q = AdT*Q + dq_i * ad(P)A_i   (meaningful on lane 7 only)
        float Uw[3], u2[3], Uv[3];
        mat3_vec(Uw, Rm, Qw);
        mat3_vec(u2, Rm, Qv);
        cross3(Uv, Tpl, Uw);
        float c1[3], c2[3], c3[3];
        cross3(c1, Pw, Aw);
        cross3(c2, Pv, Aw);
        cross3(c3, Pw, Av);
        float c8 = (r == 7) ? dqi : 0.f;
#pragma unroll
        for (int k = 0; k < 3; k++) {
          Qw[k] = Uw[k] + c8*c1[k];
          Qv[k] = Uv[k] + u2[k] + c8*(c2[k]+c3[k]);
        }
        if (r == 7) {
          float* qdst = &sQh[e][i*8];
          *(float4*)(qdst + 0) = make_float4(Qw[0], Qw[1], Qw[2], 0.f);
          *(float4*)(qdst + 4) = make_float4(Qv[0], Qv[1], Qv[2], 0.f);
        }
#pragma unroll
        for (int k = 0; k < 3; k++) { Phw[i][k] = Pw[k]; Phv[i][k] = Pv[k]; }
        SCHED_FENCE();
      }
      // backward: F' = AdT^T F via R^T(Fw + Fv x Tp), R/Tp re-read from LDS
      float Fw[3] = {0.f,0.f,0.f}, Fv[3] = {0.f,0.f,0.f};
#pragma unroll
      for (int i = NDOF-1; i >= 0; i--) {
        if (i < NDOF-1) {
          const int jn = i + 1;
          const float* src = &sRB[e][jn*12];
          float4 r0 = *(const float4*)(src + 0);
          float4 r1 = *(const float4*)(src + 4);
          float4 r2 = *(const float4*)(src + 8);
          float Rm[9] = {r0.x, r0.y, r0.z, r0.w, r1.x, r1.y, r1.z, r1.w, r2.x};
          float Tpl[3] = {r2.y, r2.z, r2.w};
          float cFT[3];
          cross3(cFT, Fv, Tpl);
          float s0[3] = {Fw[0]+cFT[0], Fw[1]+cFT[1], Fw[2]+cFT[2]};
          float nw[3], nv[3];
          mat3T_vec(nw, Rm, s0);
          mat3T_vec(nv, Rm, Fv);
          Fw[0] = nw[0]; Fw[1] = nw[1]; Fw[2] = nw[2];
          Fv[0] = nv[0]; Fv[1] = nv[1]; Fv[2] = nv[2];
        }
        float4 g4 = *(const float4*)&sG4[i][0];
        float gx = g4.x, gy = g4.y, gz = g4.z, m_ = g4.w;
        float aw[3] = {gx*Phw[i][0], gy*Phw[i][1], gz*Phw[i][2]};
        float av[3] = {m_*Phv[i][0], m_*Phv[i][1], m_*Phv[i][2]};
        float4 d0 = *(const float4*)&sQh[e][i*8 + 0];
        float4 d1 = *(const float4*)&sQh[e][i*8 + 4];
        float GDw[3] = {gx*d0.x, gy*d0.y, gz*d0.z};
        float GDv[3] = {m_*d1.x, m_*d1.y, m_*d1.z};
        float x1[3], x2[3], x3[3];
        cross3(x1, Phw[i], aw);
        cross3(x2, Phv[i], av);
        cross3(x3, Phw[i], av);
        const bool l7 = (r == 7);
#pragma unroll
        for (int k = 0; k < 3; k++) {
          Fw[k] += l7 ? (GDw[k] + x1[k] + x2[k]) : aw[k];
          Fv[k] += l7 ? (GDv[k] + x3[k])         : av[k];
        }
        float4 a0 = *(const float4*)&sA2[i][0];
        float4 a1 = *(const float4*)&sA2[i][4];
        float val = Fw[0]*a0.x + Fw[1]*a0.y + Fw[2]*a0.z
                  + Fv[0]*a0.w + Fv[1]*a1.x + Fv[2]*a1.y;
        if (r < NDOF && i >= r) MllL[(i*(i+1)/2 + r)*EP + e] = val;
        if (r == 7) biasL[i*EP + e] = val;
        SCHED_FENCE();
      }
    }
    WSYNC();

    // ---- (D) Cholesky solve, lane r==7 (reciprocal-cached) ----
    if (r == 7) {
      float Lm[28], invd[NDOF];
#pragma unroll
      for (int idx = 0; idx < 28; idx++) Lm[idx] = MllL[idx*EP + e];
      float y[NDOF];
#pragma unroll
      for (int i = 0; i < NDOF; i++) y[i] = tauL[i*EP + e] - biasL[i*EP + e];
#pragma unroll
      for (int k = 0; k < NDOF; k++) {
        float d = Lm[k*(k+1)/2 + k];
#pragma unroll
        for (int m2 = 0; m2 < k; m2++) { float l = Lm[k*(k+1)/2 + m2]; d -= l*l; }
        d = sqrtf(d);
        Lm[k*(k+1)/2 + k] = d;
        float inv = 1.0f / d;
        invd[k] = inv;
#pragma unroll
        for (int i = k+1; i < NDOF; i++) {
          float s = Lm[i*(i+1)/2 + k];
#pragma unroll
          for (int m2 = 0; m2 < k; m2++) s -= Lm[i*(i+1)/2 + m2]*Lm[k*(k+1)/2 + m2];
          Lm[i*(i+1)/2 + k] = s * inv;
        }
      }
#pragma unroll
      for (int i = 0; i < NDOF; i++) {
        float s = y[i];
#pragma unroll
        for (int m2 = 0; m2 < i; m2++) s -= Lm[i*(i+1)/2 + m2]*y[m2];
        y[i] = s * invd[i];
      }
      float qac[NDOF];
#pragma unroll
      for (int i = NDOF-1; i >= 0; i--) {
        float s = y[i];
#pragma unroll
        for (int m2 = i+1; m2 < NDOF; m2++) s -= Lm[m2*(m2+1)/2 + i]*qac[m2];
        qac[i] = s * invd[i];
      }
#pragma unroll
      for (int i = 0; i < NDOF; i++) qaccL[i*EP + e] = qac[i];
    }
    WSYNC();

    // ---- (E) RK4 stage update, lanes r<7 ----
    if (r < NDOF) {
      float a = qaccL[r*EP + e];
      float w = (st == 0 || st == 3) ? 1.0f : 2.0f;
      accq += w * dqs;
      accd += w * a;
      if (st < 3) {
        float c = (st == 2) ? HSTEP : 0.5f*HSTEP;
        qs  = q0  + c * dqs;
        dqs = dq0 + c * a;
      }
    }
  }

  const float h6 = HSTEP / 6.0f;
  float qf = 0.f;
  if (r < NDOF) {
    qf = wrap_pi(q0 + h6*accq);
    float v  = dq0 + h6*accd;
    float dqf = fminf(fmaxf(v, -MAX_VEL), MAX_VEL);
    g_out_state[b*14 + r]     = qf;
    g_out_state[b*14 + 7 + r] = dqf;
  }

  // ---- FK: per-lane leaf + 3-step shuffle tree over the 8-lane group ----
  // lane r<7: T_r = M_r * exp(A_r, qf_r); lane 7: T_7 = M_7.
  // Leftward product: lane 0 ends with (M_0 E_0)...(M_6 E_6) M_7.
  float4 m0 = *(const float4*)&sMRp[r][0];
  float4 m1 = *(const float4*)&sMRp[r][4];
  float4 m2 = *(const float4*)&sMRp[r][8];
  float SR[9], Sp[3];
  if (r < NDOF) {
    float MR[9] = {m0.x, m0.y, m0.z, m0.w, m1.x, m1.y, m1.z, m1.w, m2.x};
    float Re[9], pe[3];
    exp_se3(Aown, qf, Re, pe);
    mat3_mul(SR, MR, Re);
    float t[3];
    mat3_vec(t, MR, pe);
    Sp[0] = t[0] + m2.y; Sp[1] = t[1] + m2.z; Sp[2] = t[2] + m2.w;
  } else {
    SR[0] = m0.x; SR[1] = m0.y; SR[2] = m0.z; SR[3] = m0.w;
    SR[4] = m1.x; SR[5] = m1.y; SR[6] = m1.z; SR[7] = m1.w;
    SR[8] = m2.x;
    Sp[0] = m2.y; Sp[1] = m2.z; Sp[2] = m2.w;
  }
#pragma unroll
  for (int off = 1; off < 8; off <<= 1) {
    const int partner = base + ((r + off) & 7);
    float PRm[9], Pp[3];
#pragma unroll
    for (int k = 0; k < 9; k++) PRm[k] = __shfl(SR[k], partner, 64);
#pragma unroll
    for (int k = 0; k < 3; k++) Pp[k] = __shfl(Sp[k], partner, 64);
    float NR[9], Np[3];
    mat3_mul(NR, SR, PRm);
    mat3_vec(Np, SR, Pp);
    Np[0] += Sp[0]; Np[1] += Sp[1]; Np[2] += Sp[2];
#pragma unroll
    for (int k = 0; k < 9; k++) SR[k] = NR[k];
    Sp[0] = Np[0]; Sp[1] = Np[1]; Sp[2] = Np[2];
  }
  if (r == 0) {
    g_out_ee[b*2 + 0] = Sp[0];
    g_out_ee[b*2 + 1] = Sp[1];
  }
}

extern "C" void kernel_launch(void* const* d_in, const int* in_sizes, int n_in,
                              void* d_out, int out_size, void* d_ws, size_t ws_size,
                              hipStream_t stream) {
  const float* state  = (const float*)d_in[0];  // (16384,14)
  const float* action = (const float*)d_in[1];  // (16384,7)
  const float* M      = (const float*)d_in[2];  // (8,4,4)
  const float* A      = (const float*)d_in[3];  // (7,6)
  const float* G      = (const float*)d_in[4];  // (7,4)
  const float* grav   = (const float*)d_in[5];  // (3,)
  float* out_state = (float*)d_out;                       // (16384,14)
  float* out_ee    = (float*)d_out + (size_t)BATCH * 14;  // (16384,2)

  arm_rk4_kernel<<<BATCH / EPB, BLOCK, 0, stream>>>(
      state, action, M, A, G, grav, out_state, out_ee);
}

// Round 4
// 91.572 us; speedup vs baseline: 1.1739x; 1.1416x over previous
//
#include <hip/hip_runtime.h>
#include <math.h>

#define BLOCK 64
#define BATCH 16384
#define EPB 8      // elements per block: 8 lanes per element
#define EP 9       // element-dim stride for per-element LDS arrays
#define NDOF 7
#define ACTION_RANGE 50.0f
#define MAX_VEL 20.0f
#define HSTEP 0.1f

// BLOCK==64 -> exactly one wave per workgroup. DS ops from a single wave are
// processed in order by the LDS pipe, so cross-lane LDS communication needs
// no s_barrier — only a compiler fence to forbid reordering. (Validated:
// R14/R15/R16 all passed the harness with this scheme.)
#define WSYNC() asm volatile("" ::: "memory")
// Pin program order at joint-iteration boundaries: without s_barrier anchors
// the scheduler would hoist several joints' LDS reads ahead (the R14 184-VGPR
// balloon). Emits no instructions.
#define SCHED_FENCE() __builtin_amdgcn_sched_barrier(0)

__device__ __forceinline__ void mat3_mul(float* C, const float* A, const float* B) {
#pragma unroll
  for (int r = 0; r < 3; r++) {
#pragma unroll
    for (int c = 0; c < 3; c++) {
      C[r*3+c] = A[r*3+0]*B[0*3+c] + A[r*3+1]*B[1*3+c] + A[r*3+2]*B[2*3+c];
    }
  }
}

__device__ __forceinline__ void mat3_vec(float* y, const float* A, const float* x) {
#pragma unroll
  for (int r = 0; r < 3; r++)
    y[r] = A[r*3+0]*x[0] + A[r*3+1]*x[1] + A[r*3+2]*x[2];
}

__device__ __forceinline__ void mat3T_vec(float* y, const float* A, const float* x) {
#pragma unroll
  for (int r = 0; r < 3; r++)
    y[r] = A[0*3+r]*x[0] + A[1*3+r]*x[1] + A[2*3+r]*x[2];
}

__device__ __forceinline__ void cross3(float* y, const float* a, const float* b) {
  y[0] = a[1]*b[2] - a[2]*b[1];
  y[1] = a[2]*b[0] - a[0]*b[2];
  y[2] = a[0]*b[1] - a[1]*b[0];
}

// Rodrigues-direct for UNIT axis w (W^2 = ww^T - I):
//   R = cI + sW + (1-c)ww^T ;  G v with G = sI + (1-c)W + (th-s)ww^T
__device__ __forceinline__ void exp_se3(const float* A6, float th, float* R, float* p) {
  float w0 = A6[0], w1 = A6[1], w2 = A6[2];
  float s = __sinf(th);
  float c = __cosf(th);
  float omc = 1.0f - c, tms = th - s;
  float p00 = w0*w0, p01 = w0*w1, p02 = w0*w2;
  float p11 = w1*w1, p12 = w1*w2, p22 = w2*w2;
  R[0] = c + omc*p00;       R[1] = omc*p01 - s*w2;   R[2] = omc*p02 + s*w1;
  R[3] = omc*p01 + s*w2;    R[4] = c + omc*p11;      R[5] = omc*p12 - s*w0;
  R[6] = omc*p02 - s*w1;    R[7] = omc*p12 + s*w0;   R[8] = c + omc*p22;
  float G0 = s + tms*p00,    G1 = tms*p01 - omc*w2,  G2 = tms*p02 + omc*w1;
  float G3 = tms*p01 + omc*w2, G4 = s + tms*p11,     G5 = tms*p12 - omc*w0;
  float G6 = tms*p02 - omc*w1, G7 = tms*p12 + omc*w0, G8 = s + tms*p22;
  p[0] = G0*A6[3] + G1*A6[4] + G2*A6[5];
  p[1] = G3*A6[3] + G4*A6[4] + G5*A6[5];
  p[2] = G6*A6[3] + G7*A6[4] + G8*A6[5];
}

__device__ __forceinline__ float wrap_pi(float x) {
  const float PI_F   = 3.14159265358979323846f;
  const float TWO_PI = 6.28318530717958647692f;
  float a = x + PI_F;
  float r = a - floorf(a * (1.0f / TWO_PI)) * TWO_PI;
  return r - PI_F;
}

// R17 = R13's allocator context (launch_bounds(64,1) + SCALAR EP-stride LDS,
// the only config that landed no-spill at 112 VGPR / 41.5us) + the three
// algorithmic wins that don't raise pressure:
//  (a) Bm eliminated: adjoint payload = R[9]+Tp[3] (12 floats, was 18).
//      Bm*x = Tp x (R x); Bm^T*x = R^T(x x Tp). -27 FMA, -18 ds_write/stage.
//  (b) All __syncthreads -> WSYNC (barrier-free single-wave sync, validated
//      R14-R16) + sched_barrier(0) per joint to prevent the unroll balloon.
//  (c) Tail FK = per-lane leaf + 3-step shuffle tree (full-lane utilization).
// Attribute lessons: launch_bounds(64,4) and waves_per_eu(4,4) both drove
// the allocator to a 64-VGPR budget with 20-29MB scratch spill. Do NOT cap.
__global__ __launch_bounds__(BLOCK, 1) void arm_rk4_kernel(
    const float* __restrict__ g_state, const float* __restrict__ g_action,
    const float* __restrict__ g_M, const float* __restrict__ g_A,
    const float* __restrict__ g_G, const float* __restrict__ g_grav,
    float* __restrict__ g_out_state, float* __restrict__ g_out_ee)
{
  __shared__ float sMR[8][9];
  __shared__ float sMp[8][3];
  __shared__ float sIR[7][9];
  __shared__ float sIp[7][3];
  __shared__ float sA[7][6];
  __shared__ float sG[7][4];
  __shared__ float sg[3];
  __shared__ float sRB[7*12*EP];   // per joint: R[9], Tp[3]
  __shared__ float sQh[7*6*EP];    // per joint: Vd (lane-7 history)
  __shared__ float tauL[NDOF*EP];
  __shared__ float qaccL[NDOF*EP];

  __shared__ float MllL[28*EP];

  const int tid  = threadIdx.x;
  const int e    = tid >> 3;      // element slot 0..7
  const int r    = tid & 7;       // role 0..7
  const int base = tid & 0x38;    // first lane of this element group
  const int b    = blockIdx.x * EPB + e;

  if (tid < 8) {
    const float* Mi = g_M + tid*16;
    float a1[3] = {Mi[0], Mi[4], Mi[8]};
    float a2[3] = {Mi[1], Mi[5], Mi[9]};
    float p[3]  = {Mi[3], Mi[7], Mi[11]};
    float n1 = sqrtf(a1[0]*a1[0] + a1[1]*a1[1] + a1[2]*a1[2]);
    float b1[3] = {a1[0]/n1, a1[1]/n1, a1[2]/n1};
    float d = a2[0]*b1[0] + a2[1]*b1[1] + a2[2]*b1[2];
    float a2o[3] = {a2[0]-d*b1[0], a2[1]-d*b1[1], a2[2]-d*b1[2]};
    float n2 = sqrtf(a2o[0]*a2o[0] + a2o[1]*a2o[1] + a2o[2]*a2o[2]);
    float b2[3] = {a2o[0]/n2, a2o[1]/n2, a2o[2]/n2};
    float b3[3];
    cross3(b3, b1, b2);
    float R[9] = {b1[0], b2[0], b3[0],  b1[1], b2[1], b3[1],  b1[2], b2[2], b3[2]};
#pragma unroll
    for (int k = 0; k < 9; k++) sMR[tid][k] = R[k];
    sMp[tid][0] = p[0]; sMp[tid][1] = p[1]; sMp[tid][2] = p[2];
    if (tid < 7) {
#pragma unroll
      for (int rr = 0; rr < 3; rr++)
#pragma unroll
        for (int cc = 0; cc < 3; cc++) sIR[tid][rr*3+cc] = R[cc*3+rr];
#pragma unroll
      for (int rr = 0; rr < 3; rr++)
        sIp[tid][rr] = -(R[0*3+rr]*p[0] + R[1*3+rr]*p[1] + R[2*3+rr]*p[2]);
      const float* Ar = g_A + tid*6;
      float nw = sqrtf(Ar[0]*Ar[0] + Ar[1]*Ar[1] + Ar[2]*Ar[2]);
      sA[tid][0] = Ar[0]/nw; sA[tid][1] = Ar[1]/nw; sA[tid][2] = Ar[2]/nw;
      sA[tid][3] = Ar[3];    sA[tid][4] = Ar[4];    sA[tid][5] = Ar[5];
      sG[tid][0] = fabsf(g_G[tid*4+0]);
      sG[tid][1] = fabsf(g_G[tid*4+1]);
      sG[tid][2] = fabsf(g_G[tid*4+2]);
      sG[tid][3] = fabsf(g_G[tid*4+3]);
    }
  }
  if (tid == 0) { sg[0] = g_grav[0]; sg[1] = g_grav[1]; sg[2] = g_grav[2]; }

  float q0 = 0.f, dq0 = 0.f, qs = 0.f, dqs = 0.f;
  float accq = 0.f, accd = 0.f;
  if (r < NDOF) {
    q0  = g_state[b*14 + r];
    dq0 = g_state[b*14 + 7 + r];
    float tau = g_action[b*7 + r] * ACTION_RANGE;
    qs = q0; dqs = dq0;
    tauL[r*EP + e] = tau;
  }
  WSYNC();

#pragma unroll 1
  for (int st = 0; st < 4; st++) {
    float bias_reg[NDOF];   // valid on lane r==7

    // ---- (A) adjoint of joint r, lanes r<7: T = exp(-q A) * M^-1 ----
    if (r < NDOF) {
      float Ai[6];
#pragma unroll
      for (int k = 0; k < 6; k++) Ai[k] = sA[r][k];
      float Re[9], pe[3];
      exp_se3(Ai, -qs, Re, pe);
      float IRl[9];
#pragma unroll
      for (int k = 0; k < 9; k++) IRl[k] = sIR[r][k];
      float Tr9[9];
      mat3_mul(Tr9, Re, IRl);
      float Ipl[3] = {sIp[r][0], sIp[r][1], sIp[r][2]};
      float Tp[3];
      mat3_vec(Tp, Re, Ipl);
      Tp[0] += pe[0]; Tp[1] += pe[1]; Tp[2] += pe[2];
#pragma unroll
      for (int k = 0; k < 9; k++) sRB[(r*12 + k)*EP + e] = Tr9[k];
#pragma unroll
      for (int k = 0; k < 3; k++) sRB[(r*12 + 9 + k)*EP + e] = Tp[k];
    }
    WSYNC();
    SCHED_FENCE();

    // ---- (BC) fused forward+backward sweep, ALL 8 lanes ----
    {
      float Phw[NDOF][3], Phv[NDOF][3];
      float Pw[3] = {0.f,0.f,0.f}, Pv[3] = {0.f,0.f,0.f};
      float Qw[3] = {0.f,0.f,0.f}, Qv[3] = {0.f,0.f,0.f};
      if (r == 7) { Qv[0] = -sg[0]; Qv[1] = -sg[1]; Qv[2] = -sg[2]; }
#pragma unroll
      for (int i = 0; i < NDOF; i++) {
        float Rm[9], Tpl[3];
#pragma unroll
        for (int k = 0; k < 9; k++) Rm[k] = sRB[(i*12 + k)*EP + e];
#pragma unroll
        for (int k = 0; k < 3; k++) Tpl[k] = sRB[(i*12 + 9 + k)*EP + e];
        float dqi = __shfl(dqs, base + i, 64);
        float Aw[3] = {sA[i][0], sA[i][1], sA[i][2]};
        float Av[3] = {sA[i][3], sA[i][4], sA[i][5]};
        // P: Pw' = R Pw (+cA*Aw); Pv' = Tp x (R Pw) + R Pv (+cA*Av)
        float Tw[3], t2[3], Tv[3];
        mat3_vec(Tw, Rm, Pw);
        mat3_vec(t2, Rm, Pv);
        cross3(Tv, Tpl, Tw);
        float cA = (r == i) ? 1.f : ((r == 7) ? dqi : 0.f);
#pragma unroll
        for (int k = 0; k < 3; k++) {
          Pw[k] = Tw[k] + cA*Aw[k];
          Pv[k] = Tv[k] + t2[k] + cA*Av[k];
        }
        // Q = AdT*Q + dq_i * ad(P)A_i   (meaningful on lane 7 only)
        float Uw[3], u2[3], Uv[3];
        mat3_vec(Uw, Rm, Qw);
        mat3_vec(u2, Rm, Qv);
        cross3(Uv, Tpl, Uw);
        float c1[3], c2[3], c3[3];
        cross3(c1, Pw, Aw);
        cross3(c2, Pv, Aw);
        cross3(c3, Pw, Av);
        float c8 = (r == 7) ? dqi : 0.f;
#pragma unroll
        for (int k = 0; k < 3; k++) {
          Qw[k] = Uw[k] + c8*c1[k];
          Qv[k] = Uv[k] + u2[k] + c8*(c2[k]+c3[k]);
        }
        if (r == 7) {
#pragma unroll
          for (int k = 0; k < 3; k++) {
            sQh[(i*6 +     k)*EP + e] = Qw[k];
            sQh[(i*6 + 3 + k)*EP + e] = Qv[k];
          }
        }
#pragma unroll
        for (int k = 0; k < 3; k++) { Phw[i][k] = Pw[k]; Phv[i][k] = Pv[k]; }
        SCHED_FENCE();
      }
      // backward: F' = AdT^T F via R^T(Fw + Fv x Tp); R/Tp re-read from LDS
      float Fw[3] = {0.f, 0.f, 0.f}, Fv[3] = {0.f, 0.f, 0.f};
#pragma unroll
      for (int i = NDOF-1; i >= 0; i--) {
        if (i < NDOF-1) {
          const int jn = i + 1;
          float Rm[9], Tpl[3];
#pragma unroll
          for (int k = 0; k < 9; k++) Rm[k] = sRB[(jn*12 + k)*EP + e];
#pragma unroll
          for (int k = 0; k < 3; k++) Tpl[k] = sRB[(jn*12 + 9 + k)*EP + e];
          float cFT[3];
          cross3(cFT, Fv, Tpl);
          float s0[3] = {Fw[0]+cFT[0], Fw[1]+cFT[1], Fw[2]+cFT[2]};
          float nw[3], nv[3];
          mat3T_vec(nw, Rm, s0);
          mat3T_vec(nv, Rm, Fv);
          Fw[0] = nw[0]; Fw[1] = nw[1]; Fw[2] = nw[2];
          Fv[0] = nv[0]; Fv[1] = nv[1]; Fv[2] = nv[2];
        }
        float gx = sG[i][0], gy = sG[i][1], gz = sG[i][2], m_ = sG[i][3];
        float aw[3] = {gx*Phw[i][0], gy*Phw[i][1], gz*Phw[i][2]};
        float av[3] = {m_*Phv[i][0], m_*Phv[i][1], m_*Phv[i][2]};
        float Dw[3], Dv[3];
#pragma unroll
        for (int k = 0; k < 3; k++) {
          Dw[k] = sQh[(i*6 +     k)*EP + e];
          Dv[k] = sQh[(i*6 + 3 + k)*EP + e];
        }
        float GDw[3] = {gx*Dw[0], gy*Dw[1], gz*Dw[2]};
        float GDv[3] = {m_*Dv[0], m_*Dv[1], m_*Dv[2]};
        float x1[3], x2[3], x3[3];
        cross3(x1, Phw[i], aw);   // Vw x GVw  (lane-7 semantics)
        cross3(x2, Phv[i], av);   // Vv x GVv
        cross3(x3, Phw[i], av);   // Vw x GVv
        const bool l7 = (r == 7);
#pragma unroll
        for (int k = 0; k < 3; k++) {
          Fw[k] += l7 ? (GDw[k] + x1[k] + x2[k]) : aw[k];
          Fv[k] += l7 ? (GDv[k] + x3[k])         : av[k];
        }
        float val = Fw[0]*sA[i][0] + Fw[1]*sA[i][1] + Fw[2]*sA[i][2]
                  + Fv[0]*sA[i][3] + Fv[1]*sA[i][4] + Fv[2]*sA[i][5];
        if (r < NDOF && i >= r) MllL[(i*(i+1)/2 + r)*EP + e] = val;
        if (r == 7) bias_reg[i] = val;
        SCHED_FENCE();
      }
    }
    WSYNC();

    // ---- (D) Cholesky solve, lane r==7 (reciprocal-cached) ----
    if (r == 7) {
      float Lm[28], invd[NDOF];
#pragma unroll
      for (int idx = 0; idx < 28; idx++) Lm[idx] = MllL[idx*EP + e];
      float y[NDOF];
#pragma unroll
      for (int i = 0; i < NDOF; i++) y[i] = tauL[i*EP + e] - bias_reg[i];
#pragma unroll
      for (int k = 0; k < NDOF; k++) {
        float d = Lm[k*(k+1)/2 + k];
#pragma unroll
        for (int m2 = 0; m2 < k; m2++) { float l = Lm[k*(k+1)/2 + m2]; d -= l*l; }
        d = sqrtf(d);
        Lm[k*(k+1)/2 + k] = d;
        float inv = 1.0f / d;
        invd[k] = inv;
#pragma unroll
        for (int i = k+1; i < NDOF; i++) {
          float s = Lm[i*(i+1)/2 + k];
#pragma unroll
          for (int m2 = 0; m2 < k; m2++) s -= Lm[i*(i+1)/2 + m2]*Lm[k*(k+1)/2 + m2];
          Lm[i*(i+1)/2 + k] = s * inv;
        }
      }
#pragma unroll
      for (int i = 0; i < NDOF; i++) {
        float s = y[i];
#pragma unroll
        for (int m2 = 0; m2 < i; m2++) s -= Lm[i*(i+1)/2 + m2]*y[m2];
        y[i] = s * invd[i];
      }
      float qac[NDOF];
#pragma unroll
      for (int i = NDOF-1; i >= 0; i--) {
        float s = y[i];
#pragma unroll
        for (int m2 = i+1; m2 < NDOF; m2++) s -= Lm[m2*(m2+1)/2 + i]*qac[m2];
        qac[i] = s * invd[i];
      }
#pragma unroll
      for (int i = 0; i < NDOF; i++) qaccL[i*EP + e] = qac[i];
    }
    WSYNC();

    // ---- (E) RK4 stage update, lanes r<7 ----
    if (r < NDOF) {
      float a = qaccL[r*EP + e];
      float w = (st == 0 || st == 3) ? 1.0f : 2.0f;
      accq += w * dqs;
      accd += w * a;
      if (st < 3) {
        float c = (st == 2) ? HSTEP : 0.5f*HSTEP;
        qs  = q0  + c * dqs;
        dqs = dq0 + c * a;
      }
    }
  }

  const float h6 = HSTEP / 6.0f;
  float qf = 0.f;
  if (r < NDOF) {
    qf = wrap_pi(q0 + h6*accq);
    float v  = dq0 + h6*accd;
    float dqf = fminf(fmaxf(v, -MAX_VEL), MAX_VEL);
    g_out_state[b*14 + r]     = qf;
    g_out_state[b*14 + 7 + r] = dqf;
  }

  // ---- FK: per-lane leaf + 3-step shuffle tree over the 8-lane group ----
  // lane r<7: T_r = M_r * exp(A_r, qf_r); lane 7: T_7 = M_7.
  // Leftward product: lane 0 ends with (M_0 E_0)...(M_6 E_6) M_7; its p is EE.
  float SR[9], Sp[3];
  {
    float MR[9];
#pragma unroll
    for (int k = 0; k < 9; k++) MR[k] = sMR[r][k];
    float Mpl[3] = {sMp[r][0], sMp[r][1], sMp[r][2]};
    if (r < NDOF) {
      float Ai[6];
#pragma unroll
      for (int k = 0; k < 6; k++) Ai[k] = sA[r][k];
      float Re[9], pe[3];
      exp_se3(Ai, qf, Re, pe);
      mat3_mul(SR, MR, Re);
      float t[3];
      mat3_vec(t, MR, pe);
      Sp[0] = t[0] + Mpl[0]; Sp[1] = t[1] + Mpl[1]; Sp[2] = t[2] + Mpl[2];
    } else {
#pragma unroll
      for (int k = 0; k < 9; k++) SR[k] = MR[k];
      Sp[0] = Mpl[0]; Sp[1] = Mpl[1]; Sp[2] = Mpl[2];
    }
  }
#pragma unroll
  for (int off = 1; off < 8; off <<= 1) {
    const int partner = base + ((r + off) & 7);
    float PRm[9], Pp[3];
#pragma unroll
    for (int k = 0; k < 9; k++) PRm[k] = __shfl(SR[k], partner, 64);
#pragma unroll
    for (int k = 0; k < 3; k++) Pp[k] = __shfl(Sp[k], partner, 64);
    float NR[9], Np[3];
    mat3_mul(NR, SR, PRm);
    mat3_vec(Np, SR, Pp);
    Np[0] += Sp[0]; Np[1] += Sp[1]; Np[2] += Sp[2];
#pragma unroll
    for (int k = 0; k < 9; k++) SR[k] = NR[k];
    Sp[0] = Np[0]; Sp[1] = Np[1]; Sp[2] = Np[2];
  }
  if (r == 0) {
    g_out_ee[b*2 + 0] = Sp[0];
    g_out_ee[b*2 + 1] = Sp[1];
  }
}

extern "C" void kernel_launch(void* const* d_in, const int* in_sizes, int n_in,
                              void* d_out, int out_size, void* d_ws, size_t ws_size,
                              hipStream_t stream) {
  const float* state  = (const float*)d_in[0];  // (16384,14)
  const float* action = (const float*)d_in[1];  // (16384,7)
  const float* M      = (const float*)d_in[2];  // (8,4,4)
  const float* A      = (const float*)d_in[3];  // (7,6)
  const float* G      = (const float*)d_in[4];  // (7,4)
  const float* grav   = (const float*)d_in[5];  // (3,)
  float* out_state = (float*)d_out;                       // (16384,14)
  float* out_ee    = (float*)d_out + (size_t)BATCH * 14;  // (16384,2)

  arm_rk4_kernel<<<BATCH / EPB, BLOCK, 0, stream>>>(
      state, action, M, A, G, grav, out_state, out_ee);
}